// Round 16
// baseline (199.604 us; speedup 1.0000x reference)
//
#include <hip/hip_runtime.h>
#include <hip/hip_bf16.h>

#define BB 256      // batches
#define P 64        // cluster dim
#define MM 4096     // samples per row
#define MC 128      // chunk columns for cov staging
#define MT 256      // tile columns for apply

using bf16x8 = __attribute__((ext_vector_type(8))) short;
using f32x16 = __attribute__((ext_vector_type(16))) float;
using f32x4  = __attribute__((ext_vector_type(4))) float;
using u32x4  = __attribute__((ext_vector_type(4))) unsigned;
using u32x2  = __attribute__((ext_vector_type(2))) unsigned;

__device__ inline f32x16 MF(bf16x8 a, bf16x8 b, f32x16 c) {
    return __builtin_amdgcn_mfma_f32_32x32x16_bf16(a, b, c, 0, 0, 0);
}
__device__ inline unsigned cvtpk(float lo, float hi) {   // {bf16(lo), bf16(hi)} RTNE
    unsigned u;
    asm("v_cvt_pk_bf16_f32 %0, %1, %2" : "=v"(u) : "v"(lo), "v"(hi));
    return u;
}

// ---------------- Kernel A1: pure streaming convert x -> xpk ----------------
// No LDS, no barriers, no MFMA: the elementwise regime (guide: ~6.3 TB/s).
// xpk[b][dp][m] = {bf16 x[2dp][m], bf16 x[2dp+1][m]}. NT loads on x keep L3
// free for xpk (its consumers A2 and apply follow immediately).
__global__ __launch_bounds__(256)
void convert_kernel(const float* __restrict__ x, unsigned* __restrict__ xpk)
{
    const int bp = blockIdx.x;          // 0..2047
    const int b = bp >> 3, sub = bp & 7;
    const int t = threadIdx.x;
    const float* xb = x + (size_t)b * (P * MM) + sub * 512;
    unsigned* xpb = xpk + (size_t)b * (32 * MM) + sub * 512;
    #pragma unroll
    for (int j = 0; j < 16; ++j) {
        int slot = t + 256 * j;         // 0..4095
        int dp = slot >> 7, c4 = slot & 127;
        const float* p = xb + (size_t)(2 * dp) * MM + c4 * 4;
        f32x4 e = __builtin_nontemporal_load(reinterpret_cast<const f32x4*>(p));
        f32x4 o = __builtin_nontemporal_load(reinterpret_cast<const f32x4*>(p + MM));
        u32x4 pd;
        pd.x = cvtpk(e.x, o.x); pd.y = cvtpk(e.y, o.y);
        pd.z = cvtpk(e.z, o.z); pd.w = cvtpk(e.w, o.w);
        *reinterpret_cast<u32x4*>(xpb + (size_t)dp * MM + c4 * 4) = pd;
    }
}

// ---------------- Kernel A2: covariance partials from pre-packed bf16 ----------------
// Reads xpk (134 MB, L3-warm from A1). Stage: load dwords, v_perm-style
// unpack to m-packed LDS rows; MFMA 3 cov accs + 2 ones-accs (row sums on
// the MFMA pipe, proven R13). Epilogue: 5-pass cross-wave LDS reduction.
__global__ __launch_bounds__(256)
void covpart2_kernel(const unsigned* __restrict__ xpk, float* __restrict__ s2p,
                     float* __restrict__ s1p, int nsplit)
{
    __shared__ __align__(16) unsigned char smem[34816];  // 2 x [64][136] bf16

    const int b = blockIdx.x, sp = blockIdx.y;
    const int t = threadIdx.x;
    const int w = t >> 6, l = t & 63;
    const int lr = l & 31, lh = l >> 5;
    const int mlen = MM / nsplit;
    const unsigned* xpb = xpk + (size_t)b * (32 * MM) + (size_t)sp * mlen;

    f32x16 acc0 = {0,0,0,0,0,0,0,0,0,0,0,0,0,0,0,0};   // H00 partial
    f32x16 acc1 = {0,0,0,0,0,0,0,0,0,0,0,0,0,0,0,0};   // H01 partial
    f32x16 acc2 = {0,0,0,0,0,0,0,0,0,0,0,0,0,0,0,0};   // H11 partial
    f32x16 accse = {0,0,0,0,0,0,0,0,0,0,0,0,0,0,0,0};  // row sums 0..31
    f32x16 accso = {0,0,0,0,0,0,0,0,0,0,0,0,0,0,0,0};  // row sums 32..63
    const bf16x8 ones = {0x3F80,0x3F80,0x3F80,0x3F80,0x3F80,0x3F80,0x3F80,0x3F80};

    const int kbase = lh * 16;
    const int nch = mlen / MC;

    u32x4 v[4];
    #pragma unroll
    for (int j = 0; j < 4; ++j) {
        int slot = t + 256 * j;
        int dp = slot >> 5, c4 = slot & 31;
        v[j] = *reinterpret_cast<const u32x4*>(xpb + (size_t)dp * MM + c4 * 4);
    }

    for (int ch = 0; ch < nch; ++ch) {
        char* buf = (char*)smem + (ch & 1) * 17408;
        #pragma unroll
        for (int j = 0; j < 4; ++j) {
            int slot = t + 256 * j;
            int dp = slot >> 5, c4 = slot & 31;
            unsigned d0 = v[j].x, d1 = v[j].y, d2 = v[j].z, d3 = v[j].w;
            u32x2 he, ho;
            he.x = (d0 & 0xFFFFu) | (d1 << 16);          // rows 2dp: lo halves
            he.y = (d2 & 0xFFFFu) | (d3 << 16);
            ho.x = (d0 >> 16) | (d1 & 0xFFFF0000u);      // rows 2dp+1: hi halves
            ho.y = (d2 >> 16) | (d3 & 0xFFFF0000u);
            char* dst = buf + (2 * dp) * 272 + c4 * 8;
            *reinterpret_cast<u32x2*>(dst) = he;
            *reinterpret_cast<u32x2*>(dst + 272) = ho;
        }
        if (ch + 1 < nch) {
            const int m0 = (ch + 1) * MC;
            #pragma unroll
            for (int j = 0; j < 4; ++j) {
                int slot = t + 256 * j;
                int dp = slot >> 5, c4 = slot & 31;
                v[j] = *reinterpret_cast<const u32x4*>(xpb + (size_t)dp * MM + m0 + c4 * 4);
            }
        }
        __syncthreads();
        #pragma unroll
        for (int kk = 0; kk < 2; ++kk) {
            const int kb = (2 * w + kk) * 32 + kbase;
            bf16x8 f0 = *(const bf16x8*)(buf + lr * 272 + kb);
            bf16x8 f1 = *(const bf16x8*)(buf + (32 + lr) * 272 + kb);
            acc0 = MF(f0, f0, acc0);
            acc1 = MF(f0, f1, acc1);
            acc2 = MF(f1, f1, acc2);
            accse = MF(f0, ones, accse);
            accso = MF(f1, ones, accso);
        }
    }

    float (*T)[32][33] = reinterpret_cast<float (*)[32][33]>(smem);
    float* s2b = s2p + ((size_t)sp * BB + b) * (P * P);
    float* s1b = s1p + ((size_t)sp * BB + b) * P;

#define REDUCE_PASS(ACC, STORE)                                       \
    {                                                                 \
        __syncthreads();                                              \
        _Pragma("unroll")                                             \
        for (int n = 0; n < 16; ++n) {                                \
            int row = (n & 3) + 8 * (n >> 2) + 4 * lh;                \
            T[w][row][lr] = ACC[n];                                   \
        }                                                             \
        __syncthreads();                                              \
        _Pragma("unroll")                                             \
        for (int q = 0; q < 4; ++q) {                                 \
            int idx = t + 256 * q;                                    \
            int r = idx >> 5, c = idx & 31;                           \
            float s = T[0][r][c] + T[1][r][c] + T[2][r][c] + T[3][r][c]; \
            STORE                                                     \
        }                                                             \
    }

    REDUCE_PASS(acc0, s2b[r * 64 + c] = s;)
    REDUCE_PASS(acc1, s2b[r * 64 + 32 + c] = s; s2b[(32 + c) * 64 + r] = s;)
    REDUCE_PASS(acc2, s2b[(32 + r) * 64 + 32 + c] = s;)
    REDUCE_PASS(accse, if (c == 0) s1b[r] = s;)
    REDUCE_PASS(accso, if (c == 0) s1b[32 + r] = s;)
#undef REDUCE_PASS
}

// ---------------- Legacy fallback: self-converting covariance ----------------
__global__ __launch_bounds__(256)
void covpart_kernel(const float* __restrict__ x, float* __restrict__ s2p,
                    float* __restrict__ s1p, int nsplit)
{
    __shared__ __align__(16) unsigned char smem[34816];

    const int b = blockIdx.x, sp = blockIdx.y;
    const int t = threadIdx.x;
    const int w = t >> 6, l = t & 63;
    const int lr = l & 31, lh = l >> 5;
    const int mlen = MM / nsplit;
    const float* xb = x + (size_t)b * (P * MM) + (size_t)sp * mlen;

    f32x16 acc0 = {0,0,0,0,0,0,0,0,0,0,0,0,0,0,0,0};
    f32x16 acc1 = {0,0,0,0,0,0,0,0,0,0,0,0,0,0,0,0};
    f32x16 acc2 = {0,0,0,0,0,0,0,0,0,0,0,0,0,0,0,0};
    f32x16 accse = {0,0,0,0,0,0,0,0,0,0,0,0,0,0,0,0};
    f32x16 accso = {0,0,0,0,0,0,0,0,0,0,0,0,0,0,0,0};
    const bf16x8 ones = {0x3F80,0x3F80,0x3F80,0x3F80,0x3F80,0x3F80,0x3F80,0x3F80};

    const int kbase = lh * 16;
    const int nch = mlen / MC;

    f32x4 ve[4], vo[4];
    #pragma unroll
    for (int j = 0; j < 4; ++j) {
        int slot = t + 256 * j;
        int dp = slot >> 5, c = (slot & 31) << 2;
        const float* p = xb + (size_t)(2 * dp) * MM + c;
        ve[j] = *reinterpret_cast<const f32x4*>(p);
        vo[j] = *reinterpret_cast<const f32x4*>(p + MM);
    }

    for (int ch = 0; ch < nch; ++ch) {
        char* buf = (char*)smem + (ch & 1) * 17408;
        #pragma unroll
        for (int j = 0; j < 4; ++j) {
            int slot = t + 256 * j;
            int dp = slot >> 5, c4 = slot & 31;
            u32x2 he, ho;
            he.x = cvtpk(ve[j].x, ve[j].y); he.y = cvtpk(ve[j].z, ve[j].w);
            ho.x = cvtpk(vo[j].x, vo[j].y); ho.y = cvtpk(vo[j].z, vo[j].w);
            char* dst = buf + (2 * dp) * 272 + c4 * 8;
            *reinterpret_cast<u32x2*>(dst) = he;
            *reinterpret_cast<u32x2*>(dst + 272) = ho;
        }
        if (ch + 1 < nch) {
            const int m0 = (ch + 1) * MC;
            #pragma unroll
            for (int j = 0; j < 4; ++j) {
                int slot = t + 256 * j;
                int dp = slot >> 5, c = (slot & 31) << 2;
                const float* p = xb + (size_t)(2 * dp) * MM + m0 + c;
                ve[j] = *reinterpret_cast<const f32x4*>(p);
                vo[j] = *reinterpret_cast<const f32x4*>(p + MM);
            }
        }
        __syncthreads();
        #pragma unroll
        for (int kk = 0; kk < 2; ++kk) {
            const int kb = (2 * w + kk) * 32 + kbase;
            bf16x8 f0 = *(const bf16x8*)(buf + lr * 272 + kb);
            bf16x8 f1 = *(const bf16x8*)(buf + (32 + lr) * 272 + kb);
            acc0 = MF(f0, f0, acc0);
            acc1 = MF(f0, f1, acc1);
            acc2 = MF(f1, f1, acc2);
            accse = MF(f0, ones, accse);
            accso = MF(f1, ones, accso);
        }
    }

    float (*T)[32][33] = reinterpret_cast<float (*)[32][33]>(smem);
    float* s2b = s2p + ((size_t)sp * BB + b) * (P * P);
    float* s1b = s1p + ((size_t)sp * BB + b) * P;

#define REDUCE_PASS(ACC, STORE)                                       \
    {                                                                 \
        __syncthreads();                                              \
        _Pragma("unroll")                                             \
        for (int n = 0; n < 16; ++n) {                                \
            int row = (n & 3) + 8 * (n >> 2) + 4 * lh;                \
            T[w][row][lr] = ACC[n];                                   \
        }                                                             \
        __syncthreads();                                              \
        _Pragma("unroll")                                             \
        for (int q = 0; q < 4; ++q) {                                 \
            int idx = t + 256 * q;                                    \
            int r = idx >> 5, c = idx & 31;                           \
            float s = T[0][r][c] + T[1][r][c] + T[2][r][c] + T[3][r][c]; \
            STORE                                                     \
        }                                                             \
    }

    REDUCE_PASS(acc0, s2b[r * 64 + c] = s;)
    REDUCE_PASS(acc1, s2b[r * 64 + 32 + c] = s; s2b[(32 + c) * 64 + r] = s;)
    REDUCE_PASS(acc2, s2b[(32 + r) * 64 + 32 + c] = s;)
    REDUCE_PASS(accse, if (c == 0) s1b[r] = s;)
    REDUCE_PASS(accso, if (c == 0) s1b[32 + r] = s;)
#undef REDUCE_PASS
}

// ---------------- Kernel B: shrinkage + Newton-Schulz inverse sqrt ----------------
typedef float (*Mat68)[68];

__device__ inline void mm64f(Mat68 D, Mat68 A, Mat68 Bm, int t, float alpha, float beta)
{
    __syncthreads();
    const int r0 = (t >> 4) * 4, c0 = (t & 15) * 4;
    float acc[4][4];
    #pragma unroll
    for (int i = 0; i < 4; ++i)
        #pragma unroll
        for (int j = 0; j < 4; ++j) acc[i][j] = 0.f;
    #pragma unroll 4
    for (int k = 0; k < P; ++k) {
        float av[4], bv[4];
        *reinterpret_cast<float4*>(av) = *reinterpret_cast<const float4*>(&A[k][r0]);
        *reinterpret_cast<float4*>(bv) = *reinterpret_cast<const float4*>(&Bm[k][c0]);
        #pragma unroll
        for (int i = 0; i < 4; ++i)
            #pragma unroll
            for (int j = 0; j < 4; ++j) acc[i][j] += av[i] * bv[j];
    }
    __syncthreads();
    #pragma unroll
    for (int i = 0; i < 4; ++i)
        #pragma unroll
        for (int j = 0; j < 4; ++j)
            D[r0 + i][c0 + j] = alpha * acc[i][j] + ((r0 + i) == (c0 + j) ? beta : 0.f);
}

__global__ __launch_bounds__(256)
void whiten_kernel(const float* __restrict__ s2p, const float* __restrict__ s1p,
                   unsigned* __restrict__ sbb, float* __restrict__ tvec, int nsplit)
{
    __shared__ __align__(16) float B0[P][68], B1[P][68], B2[P][68], B3[P][68], B4[P][68];
    __shared__ float mus[P];
    __shared__ float red[2][4];
    const int b = blockIdx.x, t = threadIdx.x;

    if (t < P) {
        float s = 0.f;
        for (int sp = 0; sp < nsplit; ++sp) s += s1p[((size_t)sp * BB + b) * P + t];
        mus[t] = s * (1.0f / MM);
    }
    __syncthreads();

    float tr_part = 0.f, s2_part = 0.f;
    #pragma unroll
    for (int j = 0; j < 16; ++j) {
        int f = t + 256 * j;
        int i = f >> 6, jc = f & 63;
        float sum = 0.f;
        for (int sp = 0; sp < nsplit; ++sp)
            sum += s2p[((size_t)sp * BB + b) * (P * P) + f];
        float v = sum * (1.0f / MM) - mus[i] * mus[jc];
        B0[i][jc] = v;
        s2_part += v * v;
        if (i == jc) tr_part += v;
    }
    #pragma unroll
    for (int off = 32; off > 0; off >>= 1) {
        tr_part += __shfl_down(tr_part, off);
        s2_part += __shfl_down(s2_part, off);
    }
    if ((t & 63) == 0) { red[0][t >> 6] = tr_part; red[1][t >> 6] = s2_part; }
    __syncthreads();
    const float trace = red[0][0] + red[0][1] + red[0][2] + red[0][3];
    const float sum2  = red[1][0] + red[1][1] + red[1][2] + red[1][3];

    const float nf = (float)MM;
    const float num = (nf - 2.0f) / nf * sum2 + trace * trace;
    const float den = (nf + 2.0f) * (sum2 - trace * trace / (float)P);
    const float rho = (den > 0.f) ? fminf(num / den, 1.0f) : 1.0f;
    const float lam = trace * (1.0f / P);
    const float inv_s = 1.0f / lam;

    #pragma unroll
    for (int j = 0; j < 16; ++j) {
        int f = t + 256 * j;
        int i = f >> 6, jc = f & 63;
        float v = B0[i][jc];
        float sv = ((1.0f - rho) * v + ((i == jc) ? rho * lam : 0.f)) * inv_s;
        B0[i][jc] = sv;
        B2[i][jc] = ((i == jc) ? 1.5f : 0.f) - 0.5f * sv;
    }

    mm64f(B1, B0, B2, t, 1.f, 0.f);          // map1: Y1=A*T1, Z1=T1
    Mat68 Yc = B1, Zc = B2, Tc = B0, U = B3, V = B4;
    {
        mm64f(Tc, Zc, Yc, t, -0.5f, 1.5f);   // map2
        mm64f(U,  Yc, Tc, t, 1.f, 0.f);
        mm64f(V,  Tc, Zc, t, 1.f, 0.f);
        Mat68 tmp = Yc; Yc = U; U = tmp;
        tmp = Zc; Zc = V; V = tmp;
    }
    mm64f(Tc, Zc, Yc, t, -0.5f, 1.5f);       // map3
    mm64f(U,  Tc, Zc, t, 1.f, 0.f);          // U = A^{-1/2}
    __syncthreads();

    const float sc = rsqrtf(lam);
    unsigned* sb = sbb + (size_t)b * (P * P / 2);
    #pragma unroll
    for (int j = 0; j < 8; ++j) {
        int slot = t + 256 * j;
        int dp = slot >> 6, row = slot & 63;
        sb[slot] = cvtpk(U[row][2 * dp] * sc, U[row][2 * dp + 1] * sc);
    }
    if (t < P) {
        float tv = 0.f;
        #pragma unroll
        for (int d = 0; d < P; ++d) tv += U[t][d] * mus[d];
        tvec[b * P + t] = tv * sc;
    }
}

// ---------------- Kernel C (xpk): Z = S_hat * x - t ----------------
__global__ __launch_bounds__(256)
void apply_kernel_x(const unsigned* __restrict__ xpk, const unsigned* __restrict__ sbb,
                    const float* __restrict__ tvec, float* __restrict__ out)
{
    __shared__ unsigned Spk[32][68];
    __shared__ unsigned Xpk[32][260];
    __shared__ float tvs[P];
    const int mt = blockIdx.x, b = blockIdx.y;
    const int t = threadIdx.x;
    const int w = t >> 6, l = t & 63;
    const int lr = l & 31, lh = l >> 5;

    const unsigned* sb = sbb + (size_t)b * (P * P / 2);
    #pragma unroll
    for (int j = 0; j < 8; ++j) {
        int slot = t + 256 * j;
        Spk[slot >> 6][slot & 63] = sb[slot];
    }
    if (t < P) tvs[t] = tvec[b * P + t];

    const unsigned* xb = xpk + (size_t)b * (32 * MM) + mt * MT;
    #pragma unroll
    for (int j = 0; j < 8; ++j) {
        int slot = t + 256 * j;
        int dp = slot >> 6, m0 = (slot & 63) * 4;
        u32x4 pk = *reinterpret_cast<const u32x4*>(xb + (size_t)dp * MM + m0);
        *reinterpret_cast<u32x4*>(&Xpk[dp][m0]) = pk;
    }
    __syncthreads();

    union U8 { unsigned u[4]; bf16x8 v; };
    bf16x8 sa0[4], sa1[4];
    #pragma unroll
    for (int ks = 0; ks < 4; ++ks) {
        const int dpb = ks * 8 + lh * 4;
        U8 x0, x1;
        #pragma unroll
        for (int q = 0; q < 4; ++q) {
            x0.u[q] = Spk[dpb + q][lr];
            x1.u[q] = Spk[dpb + q][32 + lr];
        }
        sa0[ks] = x0.v;
        sa1[ks] = x1.v;
    }

    f32x16 acc00 = {0,0,0,0,0,0,0,0,0,0,0,0,0,0,0,0};
    f32x16 acc01 = {0,0,0,0,0,0,0,0,0,0,0,0,0,0,0,0};
    f32x16 acc10 = {0,0,0,0,0,0,0,0,0,0,0,0,0,0,0,0};
    f32x16 acc11 = {0,0,0,0,0,0,0,0,0,0,0,0,0,0,0,0};

    const int cq0 = (2 * w) * 32 + lr, cq1 = cq0 + 32;
    #pragma unroll
    for (int ks = 0; ks < 4; ++ks) {
        const int dpb = ks * 8 + lh * 4;
        U8 b0, b1;
        #pragma unroll
        for (int q = 0; q < 4; ++q) {
            b0.u[q] = Xpk[dpb + q][cq0];
            b1.u[q] = Xpk[dpb + q][cq1];
        }
        acc00 = MF(sa0[ks], b0.v, acc00);
        acc01 = MF(sa0[ks], b1.v, acc01);
        acc10 = MF(sa1[ks], b0.v, acc10);
        acc11 = MF(sa1[ks], b1.v, acc11);
    }

    float* ob = out + (size_t)b * (P * MM) + mt * MT;
#define STORE_TILE(ACC, RT, CQ)                                          \
    {                                                                    \
        _Pragma("unroll")                                                \
        for (int n = 0; n < 16; ++n) {                                   \
            int row = (RT) * 32 + (n & 3) + 8 * (n >> 2) + 4 * lh;       \
            __builtin_nontemporal_store(ACC[n] - tvs[row],               \
                                        ob + (size_t)row * MM + (CQ));   \
        }                                                                \
    }
    STORE_TILE(acc00, 0, cq0)
    STORE_TILE(acc01, 0, cq1)
    STORE_TILE(acc10, 1, cq0)
    STORE_TILE(acc11, 1, cq1)
#undef STORE_TILE
}

// ---------------- Kernel C (legacy fallback): reads f32 x ----------------
__global__ __launch_bounds__(256)
void apply_kernel(const float* __restrict__ x, const unsigned* __restrict__ sbb,
                  const float* __restrict__ tvec, float* __restrict__ out)
{
    __shared__ unsigned Spk[32][68];
    __shared__ unsigned Xpk[32][260];
    __shared__ float tvs[P];
    const int mt = blockIdx.x, b = blockIdx.y;
    const int t = threadIdx.x;
    const int w = t >> 6, l = t & 63;
    const int lr = l & 31, lh = l >> 5;

    const unsigned* sb = sbb + (size_t)b * (P * P / 2);
    #pragma unroll
    for (int j = 0; j < 8; ++j) {
        int slot = t + 256 * j;
        Spk[slot >> 6][slot & 63] = sb[slot];
    }
    if (t < P) tvs[t] = tvec[b * P + t];

    const float* xb = x + (size_t)b * (P * MM) + mt * MT;
    #pragma unroll
    for (int j = 0; j < 8; ++j) {
        int slot = t + 256 * j;
        int dp = slot >> 6, m0 = (slot & 63) * 4;
        const float* xr = xb + (size_t)(2 * dp) * MM + m0;
        f32x4 a = *reinterpret_cast<const f32x4*>(xr);
        f32x4 c = *reinterpret_cast<const f32x4*>(xr + MM);
        uint4 pk = make_uint4(cvtpk(a.x, c.x), cvtpk(a.y, c.y),
                              cvtpk(a.z, c.z), cvtpk(a.w, c.w));
        *reinterpret_cast<uint4*>(&Xpk[dp][m0]) = pk;
    }
    __syncthreads();

    union U8 { unsigned u[4]; bf16x8 v; };
    bf16x8 sa0[4], sa1[4];
    #pragma unroll
    for (int ks = 0; ks < 4; ++ks) {
        const int dpb = ks * 8 + lh * 4;
        U8 x0, x1;
        #pragma unroll
        for (int q = 0; q < 4; ++q) {
            x0.u[q] = Spk[dpb + q][lr];
            x1.u[q] = Spk[dpb + q][32 + lr];
        }
        sa0[ks] = x0.v;
        sa1[ks] = x1.v;
    }

    f32x16 acc00 = {0,0,0,0,0,0,0,0,0,0,0,0,0,0,0,0};
    f32x16 acc01 = {0,0,0,0,0,0,0,0,0,0,0,0,0,0,0,0};
    f32x16 acc10 = {0,0,0,0,0,0,0,0,0,0,0,0,0,0,0,0};
    f32x16 acc11 = {0,0,0,0,0,0,0,0,0,0,0,0,0,0,0,0};

    const int cq0 = (2 * w) * 32 + lr, cq1 = cq0 + 32;
    #pragma unroll
    for (int ks = 0; ks < 4; ++ks) {
        const int dpb = ks * 8 + lh * 4;
        U8 b0, b1;
        #pragma unroll
        for (int q = 0; q < 4; ++q) {
            b0.u[q] = Xpk[dpb + q][cq0];
            b1.u[q] = Xpk[dpb + q][cq1];
        }
        acc00 = MF(sa0[ks], b0.v, acc00);
        acc01 = MF(sa0[ks], b1.v, acc01);
        acc10 = MF(sa1[ks], b0.v, acc10);
        acc11 = MF(sa1[ks], b1.v, acc11);
    }

    float* ob = out + (size_t)b * (P * MM) + mt * MT;
#define STORE_TILE(ACC, RT, CQ)                                          \
    {                                                                    \
        _Pragma("unroll")                                                \
        for (int n = 0; n < 16; ++n) {                                   \
            int row = (RT) * 32 + (n & 3) + 8 * (n >> 2) + 4 * lh;       \
            __builtin_nontemporal_store(ACC[n] - tvs[row],               \
                                        ob + (size_t)row * MM + (CQ));   \
        }                                                                \
    }
    STORE_TILE(acc00, 0, cq0)
    STORE_TILE(acc01, 0, cq1)
    STORE_TILE(acc10, 1, cq0)
    STORE_TILE(acc11, 1, cq1)
#undef STORE_TILE
}

extern "C" void kernel_launch(void* const* d_in, const int* in_sizes, int n_in,
                              void* d_out, int out_size, void* d_ws, size_t ws_size,
                              hipStream_t stream)
{
    const float* x = (const float*)d_in[0];
    float* out = (float*)d_out;

    auto need = [](int ns) -> size_t {
        return ((size_t)ns * BB * P * P + (size_t)ns * BB * P
                + (size_t)BB * P * P / 2 + (size_t)BB * P) * sizeof(float);
    };
    const size_t xpk_bytes = (size_t)BB * 32 * MM * sizeof(unsigned);   // 134 MB

    int nsplit;
    bool xon;
    if (ws_size >= need(4) + xpk_bytes)      { nsplit = 4; xon = true; }
    else if (ws_size >= need(2) + xpk_bytes) { nsplit = 2; xon = true; }
    else {
        xon = false;
        nsplit = (ws_size >= need(4)) ? 4 : (ws_size >= need(2)) ? 2 : 1;
    }

    float* s2p  = (float*)d_ws;
    float* s1p  = s2p + (size_t)nsplit * BB * P * P;
    unsigned* sbb = (unsigned*)(s1p + (size_t)nsplit * BB * P);
    float* tvec = (float*)(sbb + (size_t)BB * P * P / 2);
    unsigned* xpk = (unsigned*)(tvec + (size_t)BB * P);

    if (xon) {
        convert_kernel<<<dim3(BB * 8), 256, 0, stream>>>(x, xpk);
        covpart2_kernel<<<dim3(BB, nsplit), 256, 0, stream>>>(xpk, s2p, s1p, nsplit);
        whiten_kernel<<<dim3(BB), 256, 0, stream>>>(s2p, s1p, sbb, tvec, nsplit);
        apply_kernel_x<<<dim3(MM / MT, BB), 256, 0, stream>>>(xpk, sbb, tvec, out);
    } else {
        covpart_kernel<<<dim3(BB, nsplit), 256, 0, stream>>>(x, s2p, s1p, nsplit);
        whiten_kernel<<<dim3(BB), 256, 0, stream>>>(s2p, s1p, sbb, tvec, nsplit);
        apply_kernel<<<dim3(MM / MT, BB), 256, 0, stream>>>(x, sbb, tvec, out);
    }
}

// Round 17
// 184.624 us; speedup vs baseline: 1.0811x; 1.0811x over previous
//
#include <hip/hip_runtime.h>
#include <hip/hip_bf16.h>

#define BB 256      // batches
#define P 64        // cluster dim
#define MM 4096     // samples per row
#define MC 128      // chunk columns for cov staging
#define MT 256      // tile columns for apply

using bf16x8 = __attribute__((ext_vector_type(8))) short;
using f32x16 = __attribute__((ext_vector_type(16))) float;
using f32x4  = __attribute__((ext_vector_type(4))) float;
using u32x4  = __attribute__((ext_vector_type(4))) unsigned;
using u32x2  = __attribute__((ext_vector_type(2))) unsigned;

__device__ inline f32x16 MF(bf16x8 a, bf16x8 b, f32x16 c) {
    return __builtin_amdgcn_mfma_f32_32x32x16_bf16(a, b, c, 0, 0, 0);
}
__device__ inline unsigned cvtpk(float lo, float hi) {   // {bf16(lo), bf16(hi)} RTNE
    unsigned u;
    asm("v_cvt_pk_bf16_f32 %0, %1, %2" : "=v"(u) : "v"(lo), "v"(hi));
    return u;
}

// ---------------- Kernel A: pure-bf16 MFMA covariance partials ----------------
// R17: per-block CHUNK-PHASE ROTATION. Diagnosis: row stride is exactly 16 KB,
// so the 64 row-segments of one chunk-stage share all address bits < 14 ->
// ~2 DRAM channels; and all blocks walk chunks in the same order in lockstep
// -> grid-wide channel hot-spotting (covpart ~3 TB/s vs 6.3 copy ceiling).
// Rotating each block's chunk start (addr bits 9-11) x sp slab (bits 12-13)
// spreads concurrent requests over ~32 phase classes. Same math, reordered
// f32 accumulation only.
template<bool XPK>
__global__ __launch_bounds__(256)
void covpart_kernel(const float* __restrict__ x, float* __restrict__ s2p,
                    float* __restrict__ s1p, unsigned* __restrict__ xpk, int nsplit)
{
    __shared__ __align__(16) unsigned char smem[34816];  // 2 x hi[64][136] bf16

    const int b = blockIdx.x, sp = blockIdx.y;
    const int t = threadIdx.x;
    const int w = t >> 6, l = t & 63;
    const int lr = l & 31, lh = l >> 5;
    const int mlen = MM / nsplit;
    const float* xb = x + (size_t)b * (P * MM) + (size_t)sp * mlen;
    unsigned* xpb = XPK ? (xpk + (size_t)b * (32 * MM) + (size_t)sp * mlen) : nullptr;

    f32x16 acc0 = {0,0,0,0,0,0,0,0,0,0,0,0,0,0,0,0};   // H00 partial
    f32x16 acc1 = {0,0,0,0,0,0,0,0,0,0,0,0,0,0,0,0};   // H01 partial
    f32x16 acc2 = {0,0,0,0,0,0,0,0,0,0,0,0,0,0,0,0};   // H11 partial
    f32x16 accse = {0,0,0,0,0,0,0,0,0,0,0,0,0,0,0,0};  // row sums 0..31
    f32x16 accso = {0,0,0,0,0,0,0,0,0,0,0,0,0,0,0,0};  // row sums 32..63
    const bf16x8 ones = {0x3F80,0x3F80,0x3F80,0x3F80,0x3F80,0x3F80,0x3F80,0x3F80};

    const int kbase = lh * 16;          // byte offset of lane's k-half in a slice
    const int nch = mlen / MC;          // 8 (ns=4) / 16 (ns=2) / 32 (ns=1): pow2
    const int ch0 = (b + 2 * sp) & (nch - 1);   // per-block phase rotation

    f32x4 ve[4], vo[4];
    {
        const int m0 = ch0 * MC;
        #pragma unroll
        for (int j = 0; j < 4; ++j) {
            int slot = t + 256 * j;
            int dp = slot >> 5, c = (slot & 31) << 2;
            const float* p = xb + (size_t)(2 * dp) * MM + m0 + c;
            ve[j] = *reinterpret_cast<const f32x4*>(p);
            vo[j] = *reinterpret_cast<const f32x4*>(p + MM);
        }
    }

    for (int chi = 0; chi < nch; ++chi) {
        const int ch = (chi + ch0) & (nch - 1);
        char* buf = (char*)smem + (chi & 1) * 17408;
        #pragma unroll
        for (int j = 0; j < 4; ++j) {
            int slot = t + 256 * j;
            int dp = slot >> 5, c4 = slot & 31;
            float e0 = ve[j].x, e1 = ve[j].y, e2 = ve[j].z, e3 = ve[j].w;
            float o0 = vo[j].x, o1 = vo[j].y, o2 = vo[j].z, o3 = vo[j].w;
            u32x2 he, ho;
            he.x = cvtpk(e0, e1); he.y = cvtpk(e2, e3);
            ho.x = cvtpk(o0, o1); ho.y = cvtpk(o2, o3);
            char* dst = buf + (2 * dp) * 272 + c4 * 8;
            *reinterpret_cast<u32x2*>(dst) = he;
            *reinterpret_cast<u32x2*>(dst + 272) = ho;
            if (XPK) {
                u32x4 pd;
                pd.x = cvtpk(e0, o0); pd.y = cvtpk(e1, o1);
                pd.z = cvtpk(e2, o2); pd.w = cvtpk(e3, o3);
                *reinterpret_cast<u32x4*>(xpb + (size_t)dp * MM + ch * MC + c4 * 4) = pd;
            }
        }
        if (chi + 1 < nch) {
            const int m0 = ((chi + 1 + ch0) & (nch - 1)) * MC;
            #pragma unroll
            for (int j = 0; j < 4; ++j) {
                int slot = t + 256 * j;
                int dp = slot >> 5, c = (slot & 31) << 2;
                const float* p = xb + (size_t)(2 * dp) * MM + m0 + c;
                ve[j] = *reinterpret_cast<const f32x4*>(p);
                vo[j] = *reinterpret_cast<const f32x4*>(p + MM);
            }
        }
        __syncthreads();
        #pragma unroll
        for (int kk = 0; kk < 2; ++kk) {
            const int kb = (2 * w + kk) * 32 + kbase;
            bf16x8 f0 = *(const bf16x8*)(buf + lr * 272 + kb);
            bf16x8 f1 = *(const bf16x8*)(buf + (32 + lr) * 272 + kb);
            acc0 = MF(f0, f0, acc0);
            acc1 = MF(f0, f1, acc1);
            acc2 = MF(f1, f1, acc2);
            accse = MF(f0, ones, accse);    // row sums ride the MFMA pipe
            accso = MF(f1, ones, accso);
        }
    }

    // ---- epilogue: cross-wave partial reduction via LDS, 5 passes ----
    float (*T)[32][33] = reinterpret_cast<float (*)[32][33]>(smem);  // 16.9 KB
    float* s2b = s2p + ((size_t)sp * BB + b) * (P * P);
    float* s1b = s1p + ((size_t)sp * BB + b) * P;

#define REDUCE_PASS(ACC, STORE)                                       \
    {                                                                 \
        __syncthreads();                                              \
        _Pragma("unroll")                                             \
        for (int n = 0; n < 16; ++n) {                                \
            int row = (n & 3) + 8 * (n >> 2) + 4 * lh;                \
            T[w][row][lr] = ACC[n];                                   \
        }                                                             \
        __syncthreads();                                              \
        _Pragma("unroll")                                             \
        for (int q = 0; q < 4; ++q) {                                 \
            int idx = t + 256 * q;                                    \
            int r = idx >> 5, c = idx & 31;                           \
            float s = T[0][r][c] + T[1][r][c] + T[2][r][c] + T[3][r][c]; \
            STORE                                                     \
        }                                                             \
    }

    REDUCE_PASS(acc0, s2b[r * 64 + c] = s;)
    REDUCE_PASS(acc1, s2b[r * 64 + 32 + c] = s; s2b[(32 + c) * 64 + r] = s;)
    REDUCE_PASS(acc2, s2b[(32 + r) * 64 + 32 + c] = s;)
    REDUCE_PASS(accse, if (c == 0) s1b[r] = s;)
    REDUCE_PASS(accso, if (c == 0) s1b[32 + r] = s;)
#undef REDUCE_PASS
}

// ---------------- Kernel B: shrinkage + Newton-Schulz inverse sqrt ----------------
typedef float (*Mat68)[68];

__device__ inline void mm64f(Mat68 D, Mat68 A, Mat68 Bm, int t, float alpha, float beta)
{
    __syncthreads();
    const int r0 = (t >> 4) * 4, c0 = (t & 15) * 4;
    float acc[4][4];
    #pragma unroll
    for (int i = 0; i < 4; ++i)
        #pragma unroll
        for (int j = 0; j < 4; ++j) acc[i][j] = 0.f;
    #pragma unroll 4
    for (int k = 0; k < P; ++k) {
        float av[4], bv[4];
        *reinterpret_cast<float4*>(av) = *reinterpret_cast<const float4*>(&A[k][r0]);
        *reinterpret_cast<float4*>(bv) = *reinterpret_cast<const float4*>(&Bm[k][c0]);
        #pragma unroll
        for (int i = 0; i < 4; ++i)
            #pragma unroll
            for (int j = 0; j < 4; ++j) acc[i][j] += av[i] * bv[j];
    }
    __syncthreads();
    #pragma unroll
    for (int i = 0; i < 4; ++i)
        #pragma unroll
        for (int j = 0; j < 4; ++j)
            D[r0 + i][c0 + j] = alpha * acc[i][j] + ((r0 + i) == (c0 + j) ? beta : 0.f);
}

__global__ __launch_bounds__(256)
void whiten_kernel(const float* __restrict__ s2p, const float* __restrict__ s1p,
                   unsigned* __restrict__ sbb, float* __restrict__ tvec, int nsplit)
{
    __shared__ __align__(16) float B0[P][68], B1[P][68], B2[P][68], B3[P][68], B4[P][68];
    __shared__ float mus[P];
    __shared__ float red[2][4];
    const int b = blockIdx.x, t = threadIdx.x;

    if (t < P) {
        float s = 0.f;
        for (int sp = 0; sp < nsplit; ++sp) s += s1p[((size_t)sp * BB + b) * P + t];
        mus[t] = s * (1.0f / MM);
    }
    __syncthreads();

    float tr_part = 0.f, s2_part = 0.f;
    #pragma unroll
    for (int j = 0; j < 16; ++j) {
        int f = t + 256 * j;
        int i = f >> 6, jc = f & 63;
        float sum = 0.f;
        for (int sp = 0; sp < nsplit; ++sp)
            sum += s2p[((size_t)sp * BB + b) * (P * P) + f];
        float v = sum * (1.0f / MM) - mus[i] * mus[jc];
        B0[i][jc] = v;
        s2_part += v * v;
        if (i == jc) tr_part += v;
    }
    #pragma unroll
    for (int off = 32; off > 0; off >>= 1) {
        tr_part += __shfl_down(tr_part, off);
        s2_part += __shfl_down(s2_part, off);
    }
    if ((t & 63) == 0) { red[0][t >> 6] = tr_part; red[1][t >> 6] = s2_part; }
    __syncthreads();
    const float trace = red[0][0] + red[0][1] + red[0][2] + red[0][3];
    const float sum2  = red[1][0] + red[1][1] + red[1][2] + red[1][3];

    const float nf = (float)MM;
    const float num = (nf - 2.0f) / nf * sum2 + trace * trace;
    const float den = (nf + 2.0f) * (sum2 - trace * trace / (float)P);
    const float rho = (den > 0.f) ? fminf(num / den, 1.0f) : 1.0f;
    const float lam = trace * (1.0f / P);
    const float inv_s = 1.0f / lam;

    #pragma unroll
    for (int j = 0; j < 16; ++j) {
        int f = t + 256 * j;
        int i = f >> 6, jc = f & 63;
        float v = B0[i][jc];
        float sv = ((1.0f - rho) * v + ((i == jc) ? rho * lam : 0.f)) * inv_s;
        B0[i][jc] = sv;
        B2[i][jc] = ((i == jc) ? 1.5f : 0.f) - 0.5f * sv;
    }

    // Newton-Schulz, 3 maps (spectrum in [0.73,1.27] -> error ~6e-6)
    mm64f(B1, B0, B2, t, 1.f, 0.f);          // map1: Y1=A*T1, Z1=T1
    Mat68 Yc = B1, Zc = B2, Tc = B0, U = B3, V = B4;
    {
        mm64f(Tc, Zc, Yc, t, -0.5f, 1.5f);   // map2
        mm64f(U,  Yc, Tc, t, 1.f, 0.f);
        mm64f(V,  Tc, Zc, t, 1.f, 0.f);
        Mat68 tmp = Yc; Yc = U; U = tmp;
        tmp = Zc; Zc = V; V = tmp;
    }
    mm64f(Tc, Zc, Yc, t, -0.5f, 1.5f);       // map3
    mm64f(U,  Tc, Zc, t, 1.f, 0.f);          // U = A^{-1/2}
    __syncthreads();

    const float sc = rsqrtf(lam);
    // S_hat emitted pair-packed: sb[dp*64 + row] = {bf16 S[row][2dp], bf16 S[row][2dp+1]}
    unsigned* sb = sbb + (size_t)b * (P * P / 2);
    #pragma unroll
    for (int j = 0; j < 8; ++j) {
        int slot = t + 256 * j;
        int dp = slot >> 6, row = slot & 63;
        sb[slot] = cvtpk(U[row][2 * dp] * sc, U[row][2 * dp + 1] * sc);
    }
    if (t < P) {
        float tv = 0.f;
        #pragma unroll
        for (int d = 0; d < P; ++d) tv += U[t][d] * mus[d];
        tvec[b * P + t] = tv * sc;
    }
}

// ---------------- Kernel C (xpk): Z = S_hat * x - t, reads pre-packed bf16 ----------------
__global__ __launch_bounds__(256)
void apply_kernel_x(const unsigned* __restrict__ xpk, const unsigned* __restrict__ sbb,
                    const float* __restrict__ tvec, float* __restrict__ out)
{
    __shared__ unsigned Spk[32][68];     // 8704 B
    __shared__ unsigned Xpk[32][260];    // 33280 B
    __shared__ float tvs[P];
    const int mt = blockIdx.x, b = blockIdx.y;
    const int t = threadIdx.x;
    const int w = t >> 6, l = t & 63;
    const int lr = l & 31, lh = l >> 5;

    const unsigned* sb = sbb + (size_t)b * (P * P / 2);
    #pragma unroll
    for (int j = 0; j < 8; ++j) {
        int slot = t + 256 * j;
        Spk[slot >> 6][slot & 63] = sb[slot];
    }
    if (t < P) tvs[t] = tvec[b * P + t];

    const unsigned* xb = xpk + (size_t)b * (32 * MM) + mt * MT;
    #pragma unroll
    for (int j = 0; j < 8; ++j) {
        int slot = t + 256 * j;
        int dp = slot >> 6, m0 = (slot & 63) * 4;
        u32x4 pk = *reinterpret_cast<const u32x4*>(xb + (size_t)dp * MM + m0);
        *reinterpret_cast<u32x4*>(&Xpk[dp][m0]) = pk;
    }
    __syncthreads();

    union U8 { unsigned u[4]; bf16x8 v; };
    bf16x8 sa0[4], sa1[4];
    #pragma unroll
    for (int ks = 0; ks < 4; ++ks) {
        const int dpb = ks * 8 + lh * 4;
        U8 x0, x1;
        #pragma unroll
        for (int q = 0; q < 4; ++q) {
            x0.u[q] = Spk[dpb + q][lr];
            x1.u[q] = Spk[dpb + q][32 + lr];
        }
        sa0[ks] = x0.v;
        sa1[ks] = x1.v;
    }

    f32x16 acc00 = {0,0,0,0,0,0,0,0,0,0,0,0,0,0,0,0};
    f32x16 acc01 = {0,0,0,0,0,0,0,0,0,0,0,0,0,0,0,0};
    f32x16 acc10 = {0,0,0,0,0,0,0,0,0,0,0,0,0,0,0,0};
    f32x16 acc11 = {0,0,0,0,0,0,0,0,0,0,0,0,0,0,0,0};

    const int cq0 = (2 * w) * 32 + lr, cq1 = cq0 + 32;
    #pragma unroll
    for (int ks = 0; ks < 4; ++ks) {
        const int dpb = ks * 8 + lh * 4;
        U8 b0, b1;
        #pragma unroll
        for (int q = 0; q < 4; ++q) {
            b0.u[q] = Xpk[dpb + q][cq0];
            b1.u[q] = Xpk[dpb + q][cq1];
        }
        acc00 = MF(sa0[ks], b0.v, acc00);
        acc01 = MF(sa0[ks], b1.v, acc01);
        acc10 = MF(sa1[ks], b0.v, acc10);
        acc11 = MF(sa1[ks], b1.v, acc11);
    }

    float* ob = out + (size_t)b * (P * MM) + mt * MT;
#define STORE_TILE(ACC, RT, CQ)                                          \
    {                                                                    \
        _Pragma("unroll")                                                \
        for (int n = 0; n < 16; ++n) {                                   \
            int row = (RT) * 32 + (n & 3) + 8 * (n >> 2) + 4 * lh;       \
            __builtin_nontemporal_store(ACC[n] - tvs[row],               \
                                        ob + (size_t)row * MM + (CQ));   \
        }                                                                \
    }
    STORE_TILE(acc00, 0, cq0)
    STORE_TILE(acc01, 0, cq1)
    STORE_TILE(acc10, 1, cq0)
    STORE_TILE(acc11, 1, cq1)
#undef STORE_TILE
}

// ---------------- Kernel C (legacy fallback): reads f32 x, converts in-kernel ----------------
__global__ __launch_bounds__(256)
void apply_kernel(const float* __restrict__ x, const unsigned* __restrict__ sbb,
                  const float* __restrict__ tvec, float* __restrict__ out)
{
    __shared__ unsigned Spk[32][68];
    __shared__ unsigned Xpk[32][260];
    __shared__ float tvs[P];
    const int mt = blockIdx.x, b = blockIdx.y;
    const int t = threadIdx.x;
    const int w = t >> 6, l = t & 63;
    const int lr = l & 31, lh = l >> 5;

    const unsigned* sb = sbb + (size_t)b * (P * P / 2);
    #pragma unroll
    for (int j = 0; j < 8; ++j) {
        int slot = t + 256 * j;
        Spk[slot >> 6][slot & 63] = sb[slot];
    }
    if (t < P) tvs[t] = tvec[b * P + t];

    const float* xb = x + (size_t)b * (P * MM) + mt * MT;
    #pragma unroll
    for (int j = 0; j < 8; ++j) {
        int slot = t + 256 * j;
        int dp = slot >> 6, m0 = (slot & 63) * 4;
        const float* xr = xb + (size_t)(2 * dp) * MM + m0;
        f32x4 a = *reinterpret_cast<const f32x4*>(xr);
        f32x4 c = *reinterpret_cast<const f32x4*>(xr + MM);
        uint4 pk = make_uint4(cvtpk(a.x, c.x), cvtpk(a.y, c.y),
                              cvtpk(a.z, c.z), cvtpk(a.w, c.w));
        *reinterpret_cast<uint4*>(&Xpk[dp][m0]) = pk;
    }
    __syncthreads();

    union U8 { unsigned u[4]; bf16x8 v; };
    bf16x8 sa0[4], sa1[4];
    #pragma unroll
    for (int ks = 0; ks < 4; ++ks) {
        const int dpb = ks * 8 + lh * 4;
        U8 x0, x1;
        #pragma unroll
        for (int q = 0; q < 4; ++q) {
            x0.u[q] = Spk[dpb + q][lr];
            x1.u[q] = Spk[dpb + q][32 + lr];
        }
        sa0[ks] = x0.v;
        sa1[ks] = x1.v;
    }

    f32x16 acc00 = {0,0,0,0,0,0,0,0,0,0,0,0,0,0,0,0};
    f32x16 acc01 = {0,0,0,0,0,0,0,0,0,0,0,0,0,0,0,0};
    f32x16 acc10 = {0,0,0,0,0,0,0,0,0,0,0,0,0,0,0,0};
    f32x16 acc11 = {0,0,0,0,0,0,0,0,0,0,0,0,0,0,0,0};

    const int cq0 = (2 * w) * 32 + lr, cq1 = cq0 + 32;
    #pragma unroll
    for (int ks = 0; ks < 4; ++ks) {
        const int dpb = ks * 8 + lh * 4;
        U8 b0, b1;
        #pragma unroll
        for (int q = 0; q < 4; ++q) {
            b0.u[q] = Xpk[dpb + q][cq0];
            b1.u[q] = Xpk[dpb + q][cq1];
        }
        acc00 = MF(sa0[ks], b0.v, acc00);
        acc01 = MF(sa0[ks], b1.v, acc01);
        acc10 = MF(sa1[ks], b0.v, acc10);
        acc11 = MF(sa1[ks], b1.v, acc11);
    }

    float* ob = out + (size_t)b * (P * MM) + mt * MT;
#define STORE_TILE(ACC, RT, CQ)                                          \
    {                                                                    \
        _Pragma("unroll")                                                \
        for (int n = 0; n < 16; ++n) {                                   \
            int row = (RT) * 32 + (n & 3) + 8 * (n >> 2) + 4 * lh;       \
            __builtin_nontemporal_store(ACC[n] - tvs[row],               \
                                        ob + (size_t)row * MM + (CQ));   \
        }                                                                \
    }
    STORE_TILE(acc00, 0, cq0)
    STORE_TILE(acc01, 0, cq1)
    STORE_TILE(acc10, 1, cq0)
    STORE_TILE(acc11, 1, cq1)
#undef STORE_TILE
}

extern "C" void kernel_launch(void* const* d_in, const int* in_sizes, int n_in,
                              void* d_out, int out_size, void* d_ws, size_t ws_size,
                              hipStream_t stream)
{
    const float* x = (const float*)d_in[0];
    float* out = (float*)d_out;

    // scratch: s2p[ns][B][64][64] f32 | s1p[ns][B][64] f32 |
    // sbb[B][32][64] uint | tvec[B][64] f32 | xpk[B][32][4096] uint (optional)
    auto need = [](int ns) -> size_t {
        return ((size_t)ns * BB * P * P + (size_t)ns * BB * P
                + (size_t)BB * P * P / 2 + (size_t)BB * P) * sizeof(float);
    };
    const size_t xpk_bytes = (size_t)BB * 32 * MM * sizeof(unsigned);   // 134 MB

    int nsplit;
    bool xon;
    if (ws_size >= need(4) + xpk_bytes)      { nsplit = 4; xon = true; }
    else if (ws_size >= need(2) + xpk_bytes) { nsplit = 2; xon = true; }
    else {
        xon = false;
        nsplit = (ws_size >= need(4)) ? 4 : (ws_size >= need(2)) ? 2 : 1;
    }

    float* s2p  = (float*)d_ws;
    float* s1p  = s2p + (size_t)nsplit * BB * P * P;
    unsigned* sbb = (unsigned*)(s1p + (size_t)nsplit * BB * P);
    float* tvec = (float*)(sbb + (size_t)BB * P * P / 2);
    unsigned* xpk = (unsigned*)(tvec + (size_t)BB * P);

    if (xon) {
        covpart_kernel<true><<<dim3(BB, nsplit), 256, 0, stream>>>(x, s2p, s1p, xpk, nsplit);
        whiten_kernel<<<dim3(BB), 256, 0, stream>>>(s2p, s1p, sbb, tvec, nsplit);
        apply_kernel_x<<<dim3(MM / MT, BB), 256, 0, stream>>>(xpk, sbb, tvec, out);
    } else {
        covpart_kernel<false><<<dim3(BB, nsplit), 256, 0, stream>>>(x, s2p, s1p, nullptr, nsplit);
        whiten_kernel<<<dim3(BB), 256, 0, stream>>>(s2p, s1p, sbb, tvec, nsplit);
        apply_kernel<<<dim3(MM / MT, BB), 256, 0, stream>>>(x, sbb, tvec, out);
    }
}